// Round 2
// baseline (1354.112 us; speedup 1.0000x reference)
//
#include <hip/hip_runtime.h>
#include <cstdint>
#include <cstddef>

typedef unsigned short ushort_t;
typedef unsigned int uint;

typedef __attribute__((ext_vector_type(8))) short short8;   // 8 x bf16 (4 VGPRs)
typedef __attribute__((ext_vector_type(4))) float floatx4;  // 4 x f32

#define CDIM 768

// ---------- bf16 helpers (raw ushort representation) ----------
__device__ __forceinline__ float bfu(ushort_t u) {
    return __uint_as_float(((uint)u) << 16);
}
__device__ __forceinline__ void bf2(uint u, float& lo, float& hi) {
    lo = __uint_as_float(u << 16);
    hi = __uint_as_float(u & 0xffff0000u);
}
__device__ __forceinline__ ushort_t f2bfu(float f) {
    uint u = __float_as_uint(f);
    u += 0x7fffu + ((u >> 16) & 1u);   // round-to-nearest-even
    return (ushort_t)(u >> 16);
}
__device__ __forceinline__ uint pack2(float a, float b) {     // RNE pack
    return (uint)f2bfu(a) | ((uint)f2bfu(b) << 16);
}
__device__ __forceinline__ uint pk_trunc(float lo, float hi) { // truncating pack (cheap)
    return (__float_as_uint(lo) >> 16) | (__float_as_uint(hi) & 0xffff0000u);
}
__device__ __forceinline__ void gload_lds16(const void* g, void* l) {
    __builtin_amdgcn_global_load_lds(
        (__attribute__((address_space(1))) void*)(uintptr_t)g,
        (__attribute__((address_space(3))) void*)l, 16, 0, 0);
}

// ---------- Kernel 0: convert Wq/Wk/Wv (fp32) -> bf16, RNE ----------
__global__ __launch_bounds__(256) void cvt_w(
    const float* __restrict__ Wq, const float* __restrict__ Wk,
    const float* __restrict__ Wv, ushort_t* __restrict__ wb)
{
    const int m = blockIdx.y;
    const float* src = (m == 0) ? Wq : (m == 1 ? Wk : Wv);
    ushort_t* dst = wb + (size_t)m * 589824;
    const int i = (blockIdx.x * 256 + threadIdx.x) * 8;   // 589824/8/256 = 288 blocks
    const float4 f0 = *(const float4*)(src + i);
    const float4 f1 = *(const float4*)(src + i + 4);
    uint4 u;
    u.x = pack2(f0.x, f0.y);
    u.y = pack2(f0.z, f0.w);
    u.z = pack2(f1.x, f1.y);
    u.w = pack2(f1.z, f1.w);
    *(uint4*)(dst + i) = u;
}

// ---------- Kernel 1: fused QKV projection GEMM (bf16 MFMA, fp32 A input) ----------
// C[M=32768][N=768] = A_f32[M][768] * Wb_bf16[N][768]^T + bias_f32[N] -> bf16.
// 128x128 tile, BK=64, 4 waves (2x2), each wave 64x64 via 4x4 mfma_f32_16x16x32_bf16.
__global__ __launch_bounds__(256, 2) void gemm_qkv(
    const float* __restrict__ s1, const float* __restrict__ s2,
    const ushort_t* __restrict__ wb,
    const float* __restrict__ bq, const float* __restrict__ bk, const float* __restrict__ bv,
    ushort_t* __restrict__ qo, ushort_t* __restrict__ ko, ushort_t* __restrict__ vo)
{
    const int z = blockIdx.z;
    const float* A        = (z == 0) ? s1 : s2;
    const ushort_t* W     = wb + (size_t)z * 589824;
    const float* bias     = (z == 0) ? bq : (z == 1 ? bk : bv);
    ushort_t* out         = (z == 0) ? qo : (z == 1 ? ko : vo);

    __shared__ ushort_t At[128 * 64];   // 16 KB
    __shared__ ushort_t Wt[128 * 64];   // 16 KB

    const int tid  = threadIdx.x;
    const int wave = tid >> 6;
    const int lane = tid & 63;
    const int wm = wave >> 1, wn = wave & 1;
    const int row0 = blockIdx.x * 128;   // token rows
    const int col0 = blockIdx.y * 128;   // output channels

    // W staging (bf16, async): wave stages rows [wave*32,+32); lane j -> base + j*16B
    const int srw = wave * 32 + (lane >> 3);
    const int scw = (lane & 7) * 8;
    const ushort_t* gw = W + (size_t)(col0 + srw) * CDIM + scw;

    // A staging (fp32 -> trunc bf16): per iter a wave covers 4 rows (16 float4/row)
    const int ara = wave * 32 + (lane >> 4);
    const int aca = (lane & 15) * 4;
    const float* gaf = A + (size_t)(row0 + ara) * CDIM + aca;

    floatx4 acc[4][4];
    #pragma unroll
    for (int i = 0; i < 4; ++i)
        #pragma unroll
        for (int j = 0; j < 4; ++j)
            acc[i][j] = (floatx4){0.f, 0.f, 0.f, 0.f};

    const int q4 = lane >> 4, r16 = lane & 15;

    for (int kt = 0; kt < CDIM; kt += 64) {
        __syncthreads();
        #pragma unroll
        for (int i = 0; i < 4; ++i)
            gload_lds16(gw + (size_t)i * 8 * CDIM + kt, &Wt[(wave * 32 + i * 8) * 64]);
        #pragma unroll
        for (int it = 0; it < 8; ++it) {
            const float4 f = *(const float4*)(gaf + (size_t)(it * 4) * CDIM + kt);
            *(uint2*)&At[(ara + it * 4) * 64 + aca] =
                make_uint2(pk_trunc(f.x, f.y), pk_trunc(f.z, f.w));
        }
        __syncthreads();
        #pragma unroll
        for (int ks = 0; ks < 2; ++ks) {
            short8 af[4], bfr[4];
            #pragma unroll
            for (int mt = 0; mt < 4; ++mt)
                af[mt] = *(const short8*)&At[(wm * 64 + mt * 16 + r16) * 64 + ks * 32 + q4 * 8];
            #pragma unroll
            for (int nt = 0; nt < 4; ++nt)
                bfr[nt] = *(const short8*)&Wt[(wn * 64 + nt * 16 + r16) * 64 + ks * 32 + q4 * 8];
            #pragma unroll
            for (int mt = 0; mt < 4; ++mt)
                #pragma unroll
                for (int nt = 0; nt < 4; ++nt)
                    acc[mt][nt] = __builtin_amdgcn_mfma_f32_16x16x32_bf16(
                        af[mt], bfr[nt], acc[mt][nt], 0, 0, 0);
        }
    }

    // epilogue: C/D layout col=lane&15, row=(lane>>4)*4+reg
    #pragma unroll
    for (int nt = 0; nt < 4; ++nt) {
        const int col = col0 + wn * 64 + nt * 16 + r16;
        const float bb = bias[col];
        #pragma unroll
        for (int mt = 0; mt < 4; ++mt) {
            const int row = row0 + wm * 64 + mt * 16 + q4 * 4;
            #pragma unroll
            for (int r = 0; r < 4; ++r) {
                float rv = acc[mt][nt][r] + bb;
                rv = fminf(fmaxf(rv, -30000.f), 30000.f);  // diagnostic clamp (no-op if sane)
                out[(size_t)(row + r) * CDIM + col] = f2bfu(rv);
            }
        }
    }
}

// ---------- Kernel 2: adaptive avg pool -> agent tokens (fp32) ----------
__global__ __launch_bounds__(256) void pool_agent(const ushort_t* __restrict__ q,
                                                  float* __restrict__ agent)
{
    const int c = blockIdx.x * 256 + threadIdx.x;   // gridDim.x = 3
    const int a = blockIdx.y, b = blockIdx.z;
    const ushort_t* p = q + ((size_t)(b * 4096 + a * 256)) * CDIM + c;
    float s0 = 0.f, s1 = 0.f, s2 = 0.f, s3 = 0.f;
    for (int r = 0; r < 256; r += 4) {
        s0 += bfu(p[(size_t)(r + 0) * CDIM]);
        s1 += bfu(p[(size_t)(r + 1) * CDIM]);
        s2 += bfu(p[(size_t)(r + 2) * CDIM]);
        s3 += bfu(p[(size_t)(r + 3) * CDIM]);
    }
    agent[(b * 16 + a) * CDIM + c] = (s0 + s1 + s2 + s3) * (1.0f / 256.0f);
}

// ---------- Kernel 3: stage-2 agent bias ab[h][a] (fp32 inputs) ----------
// ab = mean_{y,x} bilinear16(na_bias) + mean_p(ha_bias + wa_bias)
// jax bilinear 7->16 column sums: {2.25,2.34375,2.28125,2.25,2.28125,2.34375,2.25}
__global__ void bias_ab_k(const float* __restrict__ na, const float* __restrict__ ha,
                          const float* __restrict__ wa, float* __restrict__ ab)
{
    const int t = threadIdx.x;
    if (t >= 192) return;
    const int h = t >> 4, a = t & 15;
    const float cw[7] = {2.25f, 2.34375f, 2.28125f, 2.25f, 2.28125f, 2.34375f, 2.25f};
    float acc = 0.f;
    const float* nb = na + (h * 16 + a) * 49;
    for (int i = 0; i < 7; ++i)
        for (int j = 0; j < 7; ++j)
            acc += cw[i] * cw[j] * nb[i * 7 + j];
    acc *= (1.0f / 256.0f);
    float s = 0.f;
    for (int p = 0; p < 16; ++p)
        s += ha[(h * 16 + p) * 16 + a] + wa[(h * 16 + p) * 16 + a];
    ab[t] = acc + s * (1.0f / 16.0f);
}

// ---------- Kernel 4: stage 1 (agent -> keys/values), m-split x4 ----------
__global__ __launch_bounds__(256) void stage1(
    const ushort_t* __restrict__ kb_, const ushort_t* __restrict__ vb_,
    const float* __restrict__ agent, float* __restrict__ Sp, float* __restrict__ avp)
{
    const int h = blockIdx.x, b = blockIdx.y, z = blockIdx.z;
    const int tid = threadIdx.x;
    __shared__ float ahs[1024];          // ah * scale, [a][d]
    __shared__ ushort_t E[1024 * 24];    // [m_local][a] bf16, row padded to 48B

    for (int i = tid; i < 1024; i += 256) {
        const int a = i >> 6, d = i & 63;
        ahs[i] = agent[(b * 16 + a) * CDIM + h * 64 + d] * 0.125f;
    }
    __syncthreads();

    const int m0 = z * 1024;
    const ushort_t* kb = kb_ + ((size_t)(b * 4096 + m0)) * CDIM + h * 64;

    for (int it = 0; it < 4; ++it) {
        const int ml = tid + it * 256;
        float kr[64];
        const uint4* kp = (const uint4*)(kb + (size_t)ml * CDIM);
        #pragma unroll
        for (int jj = 0; jj < 8; ++jj) {
            uint4 u = kp[jj];
            bf2(u.x, kr[jj*8+0], kr[jj*8+1]);
            bf2(u.y, kr[jj*8+2], kr[jj*8+3]);
            bf2(u.z, kr[jj*8+4], kr[jj*8+5]);
            bf2(u.w, kr[jj*8+6], kr[jj*8+7]);
        }
        uint ep[8];
        #pragma unroll
        for (int a2 = 0; a2 < 8; ++a2) {
            float ee[2];
            #pragma unroll
            for (int hf = 0; hf < 2; ++hf) {
                const int a = a2 * 2 + hf;
                float dsum = 0.f;
                #pragma unroll
                for (int j = 0; j < 64; j += 4) {
                    const floatx4 a4 = *(const floatx4*)&ahs[a * 64 + j];
                    dsum += kr[j] * a4[0] + kr[j+1] * a4[1] + kr[j+2] * a4[2] + kr[j+3] * a4[3];
                }
                ee[hf] = __expf(fminf(dsum, 25.f));   // clamp = diagnostic, no-op if sane
            }
            ep[a2] = pack2(ee[0], ee[1]);
        }
        uint2* dst = (uint2*)&E[ml * 24];
        dst[0] = make_uint2(ep[0], ep[1]);
        dst[1] = make_uint2(ep[2], ep[3]);
        dst[2] = make_uint2(ep[4], ep[5]);
        dst[3] = make_uint2(ep[6], ep[7]);
    }
    __syncthreads();

    const int d = tid & 63, g = tid >> 6;   // wave g handles agents 4g..4g+3
    const ushort_t* vb = vb_ + ((size_t)(b * 4096 + m0)) * CDIM + h * 64 + d;
    float acc0 = 0, acc1 = 0, acc2 = 0, acc3 = 0;
    float ss0 = 0, ss1 = 0, ss2 = 0, ss3 = 0;
    for (int ml = 0; ml < 1024; ++ml) {
        const float vv = bfu(vb[(size_t)ml * CDIM]);
        const uint2 ee = *(const uint2*)&E[ml * 24 + g * 4];  // wave-uniform -> broadcast
        float e0, e1, e2, e3;
        bf2(ee.x, e0, e1);
        bf2(ee.y, e2, e3);
        acc0 += e0 * vv; ss0 += e0;
        acc1 += e1 * vv; ss1 += e1;
        acc2 += e2 * vv; ss2 += e2;
        acc3 += e3 * vv; ss3 += e3;
    }
    const int bh = b * 12 + h;
    float* avz = avp + (size_t)(z * 96 + bh) * 1024;
    avz[(g * 4 + 0) * 64 + d] = acc0;
    avz[(g * 4 + 1) * 64 + d] = acc1;
    avz[(g * 4 + 2) * 64 + d] = acc2;
    avz[(g * 4 + 3) * 64 + d] = acc3;
    if ((tid & 63) == 0) {
        float* Sz = Sp + (z * 96 + bh) * 16;
        Sz[g * 4 + 0] = ss0;
        Sz[g * 4 + 1] = ss1;
        Sz[g * 4 + 2] = ss2;
        Sz[g * 4 + 3] = ss3;
    }
}

// ---------- Kernel 5: stage 2 (queries -> agents) + fp32 output ----------
__global__ __launch_bounds__(256) void stage2(
    const ushort_t* __restrict__ q, const float* __restrict__ agent,
    const float* __restrict__ avp, const float* __restrict__ Sp,
    const float* __restrict__ ab, float* __restrict__ out)
{
    const int nb = blockIdx.x, h = blockIdx.y, b = blockIdx.z;
    const int tid = threadIdx.x;
    __shared__ float ahs[1024];   // ah * scale
    __shared__ float avn[1024];   // normalized agent_v
    __shared__ float abl[16];

    const int bh = b * 12 + h;
    for (int i = tid; i < 1024; i += 256) {
        const int a = i >> 6, d = i & 63;
        ahs[i] = agent[(b * 16 + a) * CDIM + h * 64 + d] * 0.125f;
        float num = 0.f, den = 0.f;
        #pragma unroll
        for (int zz = 0; zz < 4; ++zz) {
            num += avp[(size_t)(zz * 96 + bh) * 1024 + a * 64 + d];
            den += Sp[(zz * 96 + bh) * 16 + a];
        }
        avn[i] = num / den;
    }
    if (tid < 16) abl[tid] = ab[h * 16 + tid];
    __syncthreads();

    const int n = nb * 256 + tid;
    const ushort_t* qrow = q + ((size_t)(b * 4096 + n)) * CDIM + h * 64;
    float qr[64];
    const uint4* qp = (const uint4*)qrow;
    #pragma unroll
    for (int jj = 0; jj < 8; ++jj) {
        uint4 u = qp[jj];
        bf2(u.x, qr[jj*8+0], qr[jj*8+1]);
        bf2(u.y, qr[jj*8+2], qr[jj*8+3]);
        bf2(u.z, qr[jj*8+4], qr[jj*8+5]);
        bf2(u.w, qr[jj*8+6], qr[jj*8+7]);
    }
    float p[16];
    float psum = 0.f;
    #pragma unroll
    for (int a = 0; a < 16; ++a) {
        float dsum = abl[a];
        #pragma unroll
        for (int j = 0; j < 64; j += 4) {
            const floatx4 a4 = *(const floatx4*)&ahs[a * 64 + j];
            dsum += qr[j] * a4[0] + qr[j+1] * a4[1] + qr[j+2] * a4[2] + qr[j+3] * a4[3];
        }
        p[a] = __expf(fminf(dsum, 25.f));
        psum += p[a];
    }
    const float rinv = 1.0f / psum;
    #pragma unroll
    for (int a = 0; a < 16; ++a) p[a] *= rinv;

    float* orow = out + ((size_t)(b * 4096 + n)) * CDIM + h * 64;
    #pragma unroll
    for (int dc = 0; dc < 4; ++dc) {
        float o[16];
        #pragma unroll
        for (int j = 0; j < 16; ++j) o[j] = 0.f;
        #pragma unroll
        for (int a = 0; a < 16; ++a) {
            const float pa = p[a];
            const float* avr = &avn[a * 64 + dc * 16];
            #pragma unroll
            for (int j = 0; j < 16; ++j) o[j] += pa * avr[j];
        }
        #pragma unroll
        for (int j4 = 0; j4 < 4; ++j4) {
            float4 w;
            w.x = o[j4 * 4 + 0];
            w.y = o[j4 * 4 + 1];
            w.z = o[j4 * 4 + 2];
            w.w = o[j4 * 4 + 3];
            *(float4*)(orow + dc * 16 + j4 * 4) = w;
        }
    }
}

// ---------- launcher ----------
extern "C" void kernel_launch(void* const* d_in, const int* in_sizes, int n_in,
                              void* d_out, int out_size, void* d_ws, size_t ws_size,
                              hipStream_t stream) {
    (void)in_sizes; (void)n_in; (void)out_size; (void)ws_size;
    const float* s1 = (const float*)d_in[0];
    const float* s2 = (const float*)d_in[1];
    const float* Wq = (const float*)d_in[2];
    const float* bq = (const float*)d_in[3];
    const float* Wk = (const float*)d_in[4];
    const float* bk = (const float*)d_in[5];
    const float* Wv = (const float*)d_in[6];
    const float* bv = (const float*)d_in[7];
    // d_in[8] an_bias, d_in[10] ah_bias, d_in[11] aw_bias: softmax-invariant, unused
    const float* na = (const float*)d_in[9];
    const float* ha = (const float*)d_in[12];
    const float* wa = (const float*)d_in[13];
    float* out = (float*)d_out;

    char* ws = (char*)d_ws;
    ushort_t* q    = (ushort_t*)(ws);                 // 50,331,648 B
    ushort_t* k    = (ushort_t*)(ws + 50331648);      // 50,331,648 B
    ushort_t* v    = (ushort_t*)(ws + 100663296);     // 50,331,648 B
    float* agent   = (float*)(ws + 150994944);        //    393,216 B
    float* Sp      = (float*)(ws + 151388160);        //     24,576 B
    float* avp     = (float*)(ws + 151412736);        //  1,572,864 B
    float* ab      = (float*)(ws + 152985600);        //        768 B
    ushort_t* wb   = (ushort_t*)(ws + 152986368);     //  3,538,944 B (3x 768x768 bf16)

    cvt_w     <<<dim3(288, 3),    256, 0, stream>>>(Wq, Wk, Wv, wb);
    gemm_qkv  <<<dim3(256, 6, 3), 256, 0, stream>>>(s1, s2, wb, bq, bk, bv, q, k, v);
    pool_agent<<<dim3(3, 16, 8),  256, 0, stream>>>(q, agent);
    bias_ab_k <<<1, 256, 0, stream>>>(na, ha, wa, ab);
    stage1    <<<dim3(12, 8, 4),  256, 0, stream>>>(k, v, agent, Sp, avp);
    stage2    <<<dim3(16, 12, 8), 256, 0, stream>>>(q, agent, avp, Sp, ab, out);
}

// Round 3
// 665.441 us; speedup vs baseline: 2.0349x; 2.0349x over previous
//
#include <hip/hip_runtime.h>
#include <cstdint>
#include <cstddef>

typedef unsigned short ushort_t;
typedef unsigned int uint;

typedef __attribute__((ext_vector_type(8))) short short8;   // 8 x bf16 (4 VGPRs)
typedef __attribute__((ext_vector_type(4))) float floatx4;  // 4 x f32

#define CDIM 768

// ---------- bf16 helpers (raw ushort representation) ----------
__device__ __forceinline__ float bfu(ushort_t u) {
    return __uint_as_float(((uint)u) << 16);
}
__device__ __forceinline__ void bf2(uint u, float& lo, float& hi) {
    lo = __uint_as_float(u << 16);
    hi = __uint_as_float(u & 0xffff0000u);
}
__device__ __forceinline__ ushort_t f2bfu(float f) {
    uint u = __float_as_uint(f);
    u += 0x7fffu + ((u >> 16) & 1u);   // round-to-nearest-even
    return (ushort_t)(u >> 16);
}
__device__ __forceinline__ uint pack2(float a, float b) {     // RNE pack
    return (uint)f2bfu(a) | ((uint)f2bfu(b) << 16);
}
__device__ __forceinline__ uint pk_trunc(float lo, float hi) { // truncating pack (cheap)
    return (__float_as_uint(lo) >> 16) | (__float_as_uint(hi) & 0xffff0000u);
}
__device__ __forceinline__ void gload_lds16(const void* g, void* l) {
    __builtin_amdgcn_global_load_lds(
        (__attribute__((address_space(1))) void*)(uintptr_t)g,
        (__attribute__((address_space(3))) void*)l, 16, 0, 0);
}

// ---------- Kernel 0: convert Wq/Wk/Wv (fp32) -> bf16, RNE ----------
__global__ __launch_bounds__(256) void cvt_w(
    const float* __restrict__ Wq, const float* __restrict__ Wk,
    const float* __restrict__ Wv, ushort_t* __restrict__ wb)
{
    const int m = blockIdx.y;
    const float* src = (m == 0) ? Wq : (m == 1 ? Wk : Wv);
    ushort_t* dst = wb + (size_t)m * 589824;
    const int i = (blockIdx.x * 256 + threadIdx.x) * 8;
    const float4 f0 = *(const float4*)(src + i);
    const float4 f1 = *(const float4*)(src + i + 4);
    uint4 u;
    u.x = pack2(f0.x, f0.y);
    u.y = pack2(f0.z, f0.w);
    u.z = pack2(f1.x, f1.y);
    u.w = pack2(f1.z, f1.w);
    *(uint4*)(dst + i) = u;
}

// ---------- Kernel 1: fused QKV GEMM -> HEAD-MAJOR bf16 output ----------
// out_hm[(b*12+h)*4096 + m][64] = A_f32[b*4096+m][768] * Wb[N][768]^T + bias
__global__ __launch_bounds__(256, 2) void gemm_qkv(
    const float* __restrict__ s1, const float* __restrict__ s2,
    const ushort_t* __restrict__ wb,
    const float* __restrict__ bq, const float* __restrict__ bk, const float* __restrict__ bv,
    ushort_t* __restrict__ qo, ushort_t* __restrict__ ko, ushort_t* __restrict__ vo)
{
    const int z = blockIdx.z;
    const float* A        = (z == 0) ? s1 : s2;
    const ushort_t* W     = wb + (size_t)z * 589824;
    const float* bias     = (z == 0) ? bq : (z == 1 ? bk : bv);
    ushort_t* out         = (z == 0) ? qo : (z == 1 ? ko : vo);

    __shared__ ushort_t At[128 * 64];   // 16 KB
    __shared__ ushort_t Wt[128 * 64];   // 16 KB

    const int tid  = threadIdx.x;
    const int wave = tid >> 6;
    const int lane = tid & 63;
    const int wm = wave >> 1, wn = wave & 1;
    const int row0 = blockIdx.x * 128;   // token rows (b*4096+m)
    const int col0 = blockIdx.y * 128;   // output channels

    const int srw = wave * 32 + (lane >> 3);
    const int scw = (lane & 7) * 8;
    const ushort_t* gw = W + (size_t)(col0 + srw) * CDIM + scw;

    const int ara = wave * 32 + (lane >> 4);
    const int aca = (lane & 15) * 4;
    const float* gaf = A + (size_t)(row0 + ara) * CDIM + aca;

    floatx4 acc[4][4];
    #pragma unroll
    for (int i = 0; i < 4; ++i)
        #pragma unroll
        for (int j = 0; j < 4; ++j)
            acc[i][j] = (floatx4){0.f, 0.f, 0.f, 0.f};

    const int q4 = lane >> 4, r16 = lane & 15;

    for (int kt = 0; kt < CDIM; kt += 64) {
        __syncthreads();
        #pragma unroll
        for (int i = 0; i < 4; ++i)
            gload_lds16(gw + (size_t)i * 8 * CDIM + kt, &Wt[(wave * 32 + i * 8) * 64]);
        #pragma unroll
        for (int it = 0; it < 8; ++it) {
            const float4 f = *(const float4*)(gaf + (size_t)(it * 4) * CDIM + kt);
            *(uint2*)&At[(ara + it * 4) * 64 + aca] =
                make_uint2(pk_trunc(f.x, f.y), pk_trunc(f.z, f.w));
        }
        __syncthreads();
        #pragma unroll
        for (int ks = 0; ks < 2; ++ks) {
            short8 af[4], bfr[4];
            #pragma unroll
            for (int mt = 0; mt < 4; ++mt)
                af[mt] = *(const short8*)&At[(wm * 64 + mt * 16 + r16) * 64 + ks * 32 + q4 * 8];
            #pragma unroll
            for (int nt = 0; nt < 4; ++nt)
                bfr[nt] = *(const short8*)&Wt[(wn * 64 + nt * 16 + r16) * 64 + ks * 32 + q4 * 8];
            #pragma unroll
            for (int mt = 0; mt < 4; ++mt)
                #pragma unroll
                for (int nt = 0; nt < 4; ++nt)
                    acc[mt][nt] = __builtin_amdgcn_mfma_f32_16x16x32_bf16(
                        af[mt], bfr[nt], acc[mt][nt], 0, 0, 0);
        }
    }

    // epilogue: C/D layout col=lane&15, row=(lane>>4)*4+reg -> head-major store
    const int b = row0 >> 12;
    const int m_base = row0 & 4095;
    #pragma unroll
    for (int nt = 0; nt < 4; ++nt) {
        const int col = col0 + wn * 64 + nt * 16 + r16;
        const int h = col >> 6, d = col & 63;
        const float bb = bias[col];
        ushort_t* ob = out + ((size_t)(b * 12 + h) * 4096) * 64 + d;
        #pragma unroll
        for (int mt = 0; mt < 4; ++mt) {
            const int m = m_base + wm * 64 + mt * 16 + q4 * 4;
            #pragma unroll
            for (int r = 0; r < 4; ++r)
                ob[(size_t)(m + r) * 64] = f2bfu(acc[mt][nt][r] + bb);
        }
    }
}

// ---------- Kernel 2: adaptive avg pool over head-major q ----------
// agent_hm[bh][a][d] = mean over 256 rows of q_hm[bh][a*256 + r][d]
__global__ __launch_bounds__(256) void pool_agent(const ushort_t* __restrict__ q,
                                                  float* __restrict__ agent)
{
    const int a = blockIdx.x, bh = blockIdx.y;
    const int d = threadIdx.x & 63, rg = threadIdx.x >> 6;
    __shared__ float part[4][64];
    const ushort_t* p = q + ((size_t)bh * 4096 + a * 256 + rg) * 64 + d;
    float s = 0.f;
    for (int r = 0; r < 256; r += 4)
        s += bfu(p[(size_t)r * 64]);
    part[rg][d] = s;
    __syncthreads();
    if (threadIdx.x < 64) {
        const float tot = part[0][d] + part[1][d] + part[2][d] + part[3][d];
        agent[(size_t)bh * 1024 + a * 64 + d] = tot * (1.0f / 256.0f);
    }
}

// ---------- Kernel 3: stage-2 agent bias ab[h][a] (fp32) ----------
__global__ void bias_ab_k(const float* __restrict__ na, const float* __restrict__ ha,
                          const float* __restrict__ wa, float* __restrict__ ab)
{
    const int t = threadIdx.x;
    if (t >= 192) return;
    const int h = t >> 4, a = t & 15;
    const float cw[7] = {2.25f, 2.34375f, 2.28125f, 2.25f, 2.28125f, 2.34375f, 2.25f};
    float acc = 0.f;
    const float* nb = na + (h * 16 + a) * 49;
    for (int i = 0; i < 7; ++i)
        for (int j = 0; j < 7; ++j)
            acc += cw[i] * cw[j] * nb[i * 7 + j];
    acc *= (1.0f / 256.0f);
    float s = 0.f;
    for (int p = 0; p < 16; ++p)
        s += ha[(h * 16 + p) * 16 + a] + wa[(h * 16 + p) * 16 + a];
    ab[t] = acc + s * (1.0f / 16.0f);
}

// ---------- Kernel 4: stage 1 (agent -> keys/values), head-major, z-split x8 ----------
// grid (96 bh, 8 z). Block: 512 m rows. E in LDS [512][20] shorts (padded).
__global__ __launch_bounds__(256) void stage1(
    const ushort_t* __restrict__ k_hm, const ushort_t* __restrict__ v_hm,
    const float* __restrict__ agent, float* __restrict__ Sp, float* __restrict__ avp)
{
    const int bh = blockIdx.x, z = blockIdx.y;
    const int tid = threadIdx.x;
    __shared__ float ahs[1024];          // ah * scale, [a][d]
    __shared__ ushort_t E2[512 * 20];    // [m_local][a] bf16, row padded to 40 B

    for (int i = tid; i < 1024; i += 256)
        ahs[i] = agent[(size_t)bh * 1024 + i] * 0.125f;
    __syncthreads();

    const int m0 = z * 512;
    const ushort_t* kb = k_hm + ((size_t)bh * 4096 + m0) * 64;

    // phase 1: two rows per thread, ahs chunk shared across rows
    {
        const uint4* krA = (const uint4*)(kb + (size_t)tid * 64);
        const uint4* krB = (const uint4*)(kb + (size_t)(tid + 256) * 64);
        uint kuA[16], kuB[16];
        #pragma unroll
        for (int i = 0; i < 4; ++i) {
            uint4 ua = krA[i], ub = krB[i];
            kuA[i*4+0] = ua.x; kuA[i*4+1] = ua.y; kuA[i*4+2] = ua.z; kuA[i*4+3] = ua.w;
            kuB[i*4+0] = ub.x; kuB[i*4+1] = ub.y; kuB[i*4+2] = ub.z; kuB[i*4+3] = ub.w;
        }
        float dsA[16], dsB[16];
        #pragma unroll
        for (int a = 0; a < 16; ++a) { dsA[a] = 0.f; dsB[a] = 0.f; }
        #pragma unroll
        for (int c = 0; c < 16; ++c) {
            float a0, a1, a2, a3, b0, b1, b2, b3;
            bf2(kuA[2*c],   a0, a1); bf2(kuA[2*c+1], a2, a3);
            bf2(kuB[2*c],   b0, b1); bf2(kuB[2*c+1], b2, b3);
            #pragma unroll
            for (int a = 0; a < 16; ++a) {
                const floatx4 av = *(const floatx4*)&ahs[a * 64 + c * 4];
                dsA[a] += a0 * av[0] + a1 * av[1] + a2 * av[2] + a3 * av[3];
                dsB[a] += b0 * av[0] + b1 * av[1] + b2 * av[2] + b3 * av[3];
            }
        }
        uint eA[8], eB[8];
        #pragma unroll
        for (int a2 = 0; a2 < 8; ++a2) {
            eA[a2] = pack2(__expf(dsA[2*a2]), __expf(dsA[2*a2+1]));
            eB[a2] = pack2(__expf(dsB[2*a2]), __expf(dsB[2*a2+1]));
        }
        uint2* dA = (uint2*)&E2[(size_t)tid * 20];
        uint2* dB = (uint2*)&E2[(size_t)(tid + 256) * 20];
        dA[0] = make_uint2(eA[0], eA[1]); dA[1] = make_uint2(eA[2], eA[3]);
        dA[2] = make_uint2(eA[4], eA[5]); dA[3] = make_uint2(eA[6], eA[7]);
        dB[0] = make_uint2(eB[0], eB[1]); dB[1] = make_uint2(eB[2], eB[3]);
        dB[2] = make_uint2(eB[4], eB[5]); dB[3] = make_uint2(eB[6], eB[7]);
    }
    __syncthreads();

    // phase 2: wave g accumulates agents 4g..4g+3; v streamed contiguously
    const int d = tid & 63, g = tid >> 6;
    const ushort_t* vb = v_hm + ((size_t)bh * 4096 + m0) * 64 + d;
    float acc0 = 0, acc1 = 0, acc2 = 0, acc3 = 0;
    float ss0 = 0, ss1 = 0, ss2 = 0, ss3 = 0;
    for (int ml = 0; ml < 512; ++ml) {
        const float vv = bfu(vb[(size_t)ml * 64]);
        const uint2 ee = *(const uint2*)&E2[(size_t)ml * 20 + g * 4];  // uniform -> broadcast
        float e0, e1, e2, e3;
        bf2(ee.x, e0, e1);
        bf2(ee.y, e2, e3);
        acc0 += e0 * vv; ss0 += e0;
        acc1 += e1 * vv; ss1 += e1;
        acc2 += e2 * vv; ss2 += e2;
        acc3 += e3 * vv; ss3 += e3;
    }
    float* avz = avp + (size_t)(z * 96 + bh) * 1024;
    avz[(g * 4 + 0) * 64 + d] = acc0;
    avz[(g * 4 + 1) * 64 + d] = acc1;
    avz[(g * 4 + 2) * 64 + d] = acc2;
    avz[(g * 4 + 3) * 64 + d] = acc3;
    if (d == 0) {
        float* Sz = Sp + (z * 96 + bh) * 16;
        Sz[g * 4 + 0] = ss0;
        Sz[g * 4 + 1] = ss1;
        Sz[g * 4 + 2] = ss2;
        Sz[g * 4 + 3] = ss3;
    }
}

// ---------- Kernel 5: stage 2 (queries -> agents) + fp32 output ----------
// grid (8 nb, 96 bh). 2 rows/thread; LDS broadcasts amortized across rows.
__global__ __launch_bounds__(256) void stage2(
    const ushort_t* __restrict__ q_hm, const float* __restrict__ avp,
    const float* __restrict__ Sp, const float* __restrict__ agent,
    const float* __restrict__ ab, float* __restrict__ out)
{
    const int nb = blockIdx.x, bh = blockIdx.y;
    const int b = bh / 12, h = bh % 12;
    const int tid = threadIdx.x;
    __shared__ float ahs[1024];   // ah * scale
    __shared__ float avn[1024];   // normalized agent_v
    __shared__ float abl[16];

    for (int i = tid; i < 1024; i += 256) {
        const int a = i >> 6;
        ahs[i] = agent[(size_t)bh * 1024 + i] * 0.125f;
        float num = 0.f, den = 0.f;
        #pragma unroll
        for (int zz = 0; zz < 8; ++zz) {
            num += avp[(size_t)(zz * 96 + bh) * 1024 + i];
            den += Sp[(zz * 96 + bh) * 16 + a];
        }
        avn[i] = num / den;
    }
    if (tid < 16) abl[tid] = ab[h * 16 + tid];
    __syncthreads();

    const int n0 = nb * 512;
    const uint4* qrA = (const uint4*)(q_hm + ((size_t)bh * 4096 + n0 + tid) * 64);
    const uint4* qrB = (const uint4*)(q_hm + ((size_t)bh * 4096 + n0 + tid + 256) * 64);
    uint quA[16], quB[16];
    #pragma unroll
    for (int i = 0; i < 4; ++i) {
        uint4 ua = qrA[i], ub = qrB[i];
        quA[i*4+0] = ua.x; quA[i*4+1] = ua.y; quA[i*4+2] = ua.z; quA[i*4+3] = ua.w;
        quB[i*4+0] = ub.x; quB[i*4+1] = ub.y; quB[i*4+2] = ub.z; quB[i*4+3] = ub.w;
    }
    float dsA[16], dsB[16];
    #pragma unroll
    for (int a = 0; a < 16; ++a) { float t = abl[a]; dsA[a] = t; dsB[a] = t; }
    #pragma unroll
    for (int c = 0; c < 16; ++c) {
        float a0, a1, a2, a3, b0, b1, b2, b3;
        bf2(quA[2*c],   a0, a1); bf2(quA[2*c+1], a2, a3);
        bf2(quB[2*c],   b0, b1); bf2(quB[2*c+1], b2, b3);
        #pragma unroll
        for (int a = 0; a < 16; ++a) {
            const floatx4 av = *(const floatx4*)&ahs[a * 64 + c * 4];
            dsA[a] += a0 * av[0] + a1 * av[1] + a2 * av[2] + a3 * av[3];
            dsB[a] += b0 * av[0] + b1 * av[1] + b2 * av[2] + b3 * av[3];
        }
    }
    float psA = 0.f, psB = 0.f;
    #pragma unroll
    for (int a = 0; a < 16; ++a) {
        dsA[a] = __expf(dsA[a]); psA += dsA[a];
        dsB[a] = __expf(dsB[a]); psB += dsB[a];
    }
    const float rA = 1.0f / psA, rB = 1.0f / psB;
    #pragma unroll
    for (int a = 0; a < 16; ++a) { dsA[a] *= rA; dsB[a] *= rB; }

    float* oA = out + ((size_t)b * 4096 + n0 + tid) * CDIM + h * 64;
    float* oB = oA + (size_t)256 * CDIM;
    #pragma unroll
    for (int dc = 0; dc < 16; ++dc) {
        floatx4 sA = {0.f, 0.f, 0.f, 0.f}, sB = {0.f, 0.f, 0.f, 0.f};
        #pragma unroll
        for (int a = 0; a < 16; ++a) {
            const floatx4 av = *(const floatx4*)&avn[a * 64 + dc * 4];
            sA += dsA[a] * av;
            sB += dsB[a] * av;
        }
        *(floatx4*)(oA + dc * 4) = sA;
        *(floatx4*)(oB + dc * 4) = sB;
    }
}

// ---------- launcher ----------
extern "C" void kernel_launch(void* const* d_in, const int* in_sizes, int n_in,
                              void* d_out, int out_size, void* d_ws, size_t ws_size,
                              hipStream_t stream) {
    (void)in_sizes; (void)n_in; (void)out_size; (void)ws_size;
    const float* s1 = (const float*)d_in[0];
    const float* s2 = (const float*)d_in[1];
    const float* Wq = (const float*)d_in[2];
    const float* bq = (const float*)d_in[3];
    const float* Wk = (const float*)d_in[4];
    const float* bk = (const float*)d_in[5];
    const float* Wv = (const float*)d_in[6];
    const float* bv = (const float*)d_in[7];
    const float* na = (const float*)d_in[9];
    const float* ha = (const float*)d_in[12];
    const float* wa = (const float*)d_in[13];
    float* out = (float*)d_out;

    char* ws = (char*)d_ws;
    ushort_t* q_hm = (ushort_t*)(ws);                 // 50,331,648 B  [96][4096][64]
    ushort_t* k_hm = (ushort_t*)(ws + 50331648);      // 50,331,648 B
    ushort_t* v_hm = (ushort_t*)(ws + 100663296);     // 50,331,648 B
    float* agent   = (float*)(ws + 150994944);        //    393,216 B  [96][16][64]
    float* Sp      = (float*)(ws + 151388160);        //     49,152 B  [8][96][16]
    float* avp     = (float*)(ws + 151437312);        //  3,145,728 B  [8][96][16][64]
    float* ab      = (float*)(ws + 154583040);        //        768 B
    ushort_t* wb   = (ushort_t*)(ws + 154583808);     //  3,538,944 B

    cvt_w     <<<dim3(288, 3),    256, 0, stream>>>(Wq, Wk, Wv, wb);
    gemm_qkv  <<<dim3(256, 6, 3), 256, 0, stream>>>(s1, s2, wb, bq, bk, bv, q_hm, k_hm, v_hm);
    pool_agent<<<dim3(16, 96),    256, 0, stream>>>(q_hm, agent);
    bias_ab_k <<<1, 256, 0, stream>>>(na, ha, wa, ab);
    stage1    <<<dim3(96, 8),     256, 0, stream>>>(k_hm, v_hm, agent, Sp, avp);
    stage2    <<<dim3(8, 96),     256, 0, stream>>>(q_hm, avp, Sp, agent, ab, out);
}

// Round 4
// 558.904 us; speedup vs baseline: 2.4228x; 1.1906x over previous
//
#include <hip/hip_runtime.h>
#include <cstdint>
#include <cstddef>

typedef unsigned short ushort_t;
typedef unsigned int uint;

typedef __attribute__((ext_vector_type(8))) short short8;   // 8 x bf16 (4 VGPRs)
typedef __attribute__((ext_vector_type(4))) float floatx4;  // 4 x f32

#define CDIM 768

// ---------- bf16 helpers (raw ushort representation) ----------
__device__ __forceinline__ float bfu(ushort_t u) {
    return __uint_as_float(((uint)u) << 16);
}
__device__ __forceinline__ void bf2(uint u, float& lo, float& hi) {
    lo = __uint_as_float(u << 16);
    hi = __uint_as_float(u & 0xffff0000u);
}
__device__ __forceinline__ ushort_t f2bfu(float f) {
    uint u = __float_as_uint(f);
    u += 0x7fffu + ((u >> 16) & 1u);   // round-to-nearest-even
    return (ushort_t)(u >> 16);
}
__device__ __forceinline__ uint pack2(float a, float b) {     // RNE pack
    return (uint)f2bfu(a) | ((uint)f2bfu(b) << 16);
}
__device__ __forceinline__ void gload_lds16(const void* g, void* l) {
    __builtin_amdgcn_global_load_lds(
        (__attribute__((address_space(1))) void*)(uintptr_t)g,
        (__attribute__((address_space(3))) void*)l, 16, 0, 0);
}

// ---------- Kernel 0a: convert Wq/Wk/Wv (fp32) -> bf16, RNE ----------
__global__ __launch_bounds__(256) void cvt_w(
    const float* __restrict__ Wq, const float* __restrict__ Wk,
    const float* __restrict__ Wv, ushort_t* __restrict__ wb)
{
    const int m = blockIdx.y;
    const float* src = (m == 0) ? Wq : (m == 1 ? Wk : Wv);
    ushort_t* dst = wb + (size_t)m * 589824;
    const int i = (blockIdx.x * 256 + threadIdx.x) * 8;
    const float4 f0 = *(const float4*)(src + i);
    const float4 f1 = *(const float4*)(src + i + 4);
    uint4 u;
    u.x = pack2(f0.x, f0.y);
    u.y = pack2(f0.z, f0.w);
    u.z = pack2(f1.x, f1.y);
    u.w = pack2(f1.z, f1.w);
    *(uint4*)(dst + i) = u;
}

// ---------- Kernel 0b: convert s1/s2 (fp32) -> bf16 activations ----------
__global__ __launch_bounds__(256) void cvt_a(
    const float* __restrict__ s1, const float* __restrict__ s2,
    ushort_t* __restrict__ ab)
{
    const int m = blockIdx.y;
    const float* src = (m == 0) ? s1 : s2;
    ushort_t* dst = ab + (size_t)m * 25165824;
    const size_t i = ((size_t)blockIdx.x * 256 + threadIdx.x) * 8;  // 12288 blocks
    const float4 f0 = *(const float4*)(src + i);
    const float4 f1 = *(const float4*)(src + i + 4);
    uint4 u;
    u.x = pack2(f0.x, f0.y);
    u.y = pack2(f0.z, f0.w);
    u.z = pack2(f1.x, f1.y);
    u.w = pack2(f1.z, f1.w);
    *(uint4*)(dst + i) = u;
}

// ---------- Kernel 1: fused QKV GEMM (all-bf16, swizzled LDS) ----------
// out_hm[(b*12+h)*4096 + m][64] = Ab[b*4096+m][768] * Wb[N][768]^T + bias
// LDS tile layout XOR-swizzled in 16B chunks: (row, c) stored at (row, c ^ (row&7)).
__global__ __launch_bounds__(256, 2) void gemm_qkv(
    const ushort_t* __restrict__ ab, const ushort_t* __restrict__ wb,
    const float* __restrict__ bq, const float* __restrict__ bk, const float* __restrict__ bv,
    ushort_t* __restrict__ qo, ushort_t* __restrict__ ko, ushort_t* __restrict__ vo)
{
    const int z = blockIdx.z;
    const ushort_t* A     = ab + (size_t)(z != 0) * 25165824;
    const ushort_t* W     = wb + (size_t)z * 589824;
    const float* bias     = (z == 0) ? bq : (z == 1 ? bk : bv);
    ushort_t* out         = (z == 0) ? qo : (z == 1 ? ko : vo);

    __shared__ ushort_t At[128 * 64];   // 16 KB
    __shared__ ushort_t Wt[128 * 64];   // 16 KB

    const int tid  = threadIdx.x;
    const int wave = tid >> 6;
    const int lane = tid & 63;
    const int wm = wave >> 1, wn = wave & 1;
    const int row0 = blockIdx.x * 128;   // token rows (b*4096+m)
    const int col0 = blockIdx.y * 128;   // output channels

    // staging: lane j covers row_off = j>>3, source chunk = (j&7) ^ (j>>3)
    // (row&7 == j>>3 because wave*32 and i*8 are multiples of 8)
    const int sro = lane >> 3;
    const int sch = ((lane & 7) ^ sro) * 8;
    const ushort_t* gaBase = A + (size_t)(row0 + wave * 32 + sro) * CDIM + sch;
    const ushort_t* gwBase = W + (size_t)(col0 + wave * 32 + sro) * CDIM + sch;

    floatx4 acc[4][4];
    #pragma unroll
    for (int i = 0; i < 4; ++i)
        #pragma unroll
        for (int j = 0; j < 4; ++j)
            acc[i][j] = (floatx4){0.f, 0.f, 0.f, 0.f};

    const int q4 = lane >> 4, r16 = lane & 15;

    for (int kt = 0; kt < CDIM; kt += 64) {
        __syncthreads();
        #pragma unroll
        for (int i = 0; i < 4; ++i) {
            gload_lds16(gaBase + (size_t)i * 8 * CDIM + kt, &At[(wave * 32 + i * 8) * 64]);
            gload_lds16(gwBase + (size_t)i * 8 * CDIM + kt, &Wt[(wave * 32 + i * 8) * 64]);
        }
        __syncthreads();
        #pragma unroll
        for (int ks = 0; ks < 2; ++ks) {
            short8 af[4], bfr[4];
            #pragma unroll
            for (int mt = 0; mt < 4; ++mt) {
                const int row = wm * 64 + mt * 16 + r16;
                const int ch  = (ks * 4 + q4) ^ (row & 7);
                af[mt] = *(const short8*)&At[row * 64 + ch * 8];
            }
            #pragma unroll
            for (int nt = 0; nt < 4; ++nt) {
                const int row = wn * 64 + nt * 16 + r16;
                const int ch  = (ks * 4 + q4) ^ (row & 7);
                bfr[nt] = *(const short8*)&Wt[row * 64 + ch * 8];
            }
            #pragma unroll
            for (int mt = 0; mt < 4; ++mt)
                #pragma unroll
                for (int nt = 0; nt < 4; ++nt)
                    acc[mt][nt] = __builtin_amdgcn_mfma_f32_16x16x32_bf16(
                        af[mt], bfr[nt], acc[mt][nt], 0, 0, 0);
        }
    }

    // epilogue: C/D layout col=lane&15, row=(lane>>4)*4+reg -> head-major store
    const int b = row0 >> 12;
    const int m_base = row0 & 4095;
    #pragma unroll
    for (int nt = 0; nt < 4; ++nt) {
        const int col = col0 + wn * 64 + nt * 16 + r16;
        const int h = col >> 6, d = col & 63;
        const float bb = bias[col];
        ushort_t* ob = out + ((size_t)(b * 12 + h) * 4096) * 64 + d;
        #pragma unroll
        for (int mt = 0; mt < 4; ++mt) {
            const int m = m_base + wm * 64 + mt * 16 + q4 * 4;
            #pragma unroll
            for (int r = 0; r < 4; ++r)
                ob[(size_t)(m + r) * 64] = f2bfu(acc[mt][nt][r] + bb);
        }
    }
}

// ---------- Kernel 2: adaptive avg pool over head-major q ----------
__global__ __launch_bounds__(256) void pool_agent(const ushort_t* __restrict__ q,
                                                  float* __restrict__ agent)
{
    const int a = blockIdx.x, bh = blockIdx.y;
    const int d = threadIdx.x & 63, rg = threadIdx.x >> 6;
    __shared__ float part[4][64];
    const ushort_t* p = q + ((size_t)bh * 4096 + a * 256 + rg) * 64 + d;
    float s = 0.f;
    for (int r = 0; r < 256; r += 4)
        s += bfu(p[(size_t)r * 64]);
    part[rg][d] = s;
    __syncthreads();
    if (threadIdx.x < 64) {
        const float tot = part[0][d] + part[1][d] + part[2][d] + part[3][d];
        agent[(size_t)bh * 1024 + a * 64 + d] = tot * (1.0f / 256.0f);
    }
}

// ---------- Kernel 3: stage-2 agent bias ab[h][a] (fp32) ----------
__global__ void bias_ab_k(const float* __restrict__ na, const float* __restrict__ ha,
                          const float* __restrict__ wa, float* __restrict__ ab)
{
    const int t = threadIdx.x;
    if (t >= 192) return;
    const int h = t >> 4, a = t & 15;
    const float cw[7] = {2.25f, 2.34375f, 2.28125f, 2.25f, 2.28125f, 2.34375f, 2.25f};
    float acc = 0.f;
    const float* nb = na + (h * 16 + a) * 49;
    for (int i = 0; i < 7; ++i)
        for (int j = 0; j < 7; ++j)
            acc += cw[i] * cw[j] * nb[i * 7 + j];
    acc *= (1.0f / 256.0f);
    float s = 0.f;
    for (int p = 0; p < 16; ++p)
        s += ha[(h * 16 + p) * 16 + a] + wa[(h * 16 + p) * 16 + a];
    ab[t] = acc + s * (1.0f / 16.0f);
}

// ---------- Kernel 4: stage 1 (agent -> keys/values), head-major, z-split x8 ----------
__global__ __launch_bounds__(256) void stage1(
    const ushort_t* __restrict__ k_hm, const ushort_t* __restrict__ v_hm,
    const float* __restrict__ agent, float* __restrict__ Sp, float* __restrict__ avp)
{
    const int bh = blockIdx.x, z = blockIdx.y;
    const int tid = threadIdx.x;
    __shared__ float ahs[1024];          // ah * scale, [a][d]
    __shared__ ushort_t E2[512 * 20];    // [m_local][a] bf16, row padded to 40 B

    for (int i = tid; i < 1024; i += 256)
        ahs[i] = agent[(size_t)bh * 1024 + i] * 0.125f;
    __syncthreads();

    const int m0 = z * 512;
    const ushort_t* kb = k_hm + ((size_t)bh * 4096 + m0) * 64;

    {
        const uint4* krA = (const uint4*)(kb + (size_t)tid * 64);
        const uint4* krB = (const uint4*)(kb + (size_t)(tid + 256) * 64);
        uint kuA[16], kuB[16];
        #pragma unroll
        for (int i = 0; i < 4; ++i) {
            uint4 ua = krA[i], ub = krB[i];
            kuA[i*4+0] = ua.x; kuA[i*4+1] = ua.y; kuA[i*4+2] = ua.z; kuA[i*4+3] = ua.w;
            kuB[i*4+0] = ub.x; kuB[i*4+1] = ub.y; kuB[i*4+2] = ub.z; kuB[i*4+3] = ub.w;
        }
        float dsA[16], dsB[16];
        #pragma unroll
        for (int a = 0; a < 16; ++a) { dsA[a] = 0.f; dsB[a] = 0.f; }
        #pragma unroll
        for (int c = 0; c < 16; ++c) {
            float a0, a1, a2, a3, b0, b1, b2, b3;
            bf2(kuA[2*c],   a0, a1); bf2(kuA[2*c+1], a2, a3);
            bf2(kuB[2*c],   b0, b1); bf2(kuB[2*c+1], b2, b3);
            #pragma unroll
            for (int a = 0; a < 16; ++a) {
                const floatx4 av = *(const floatx4*)&ahs[a * 64 + c * 4];
                dsA[a] += a0 * av[0] + a1 * av[1] + a2 * av[2] + a3 * av[3];
                dsB[a] += b0 * av[0] + b1 * av[1] + b2 * av[2] + b3 * av[3];
            }
        }
        uint eA[8], eB[8];
        #pragma unroll
        for (int a2 = 0; a2 < 8; ++a2) {
            eA[a2] = pack2(__expf(dsA[2*a2]), __expf(dsA[2*a2+1]));
            eB[a2] = pack2(__expf(dsB[2*a2]), __expf(dsB[2*a2+1]));
        }
        uint2* dA = (uint2*)&E2[(size_t)tid * 20];
        uint2* dB = (uint2*)&E2[(size_t)(tid + 256) * 20];
        dA[0] = make_uint2(eA[0], eA[1]); dA[1] = make_uint2(eA[2], eA[3]);
        dA[2] = make_uint2(eA[4], eA[5]); dA[3] = make_uint2(eA[6], eA[7]);
        dB[0] = make_uint2(eB[0], eB[1]); dB[1] = make_uint2(eB[2], eB[3]);
        dB[2] = make_uint2(eB[4], eB[5]); dB[3] = make_uint2(eB[6], eB[7]);
    }
    __syncthreads();

    const int d = tid & 63, g = tid >> 6;
    const ushort_t* vb = v_hm + ((size_t)bh * 4096 + m0) * 64 + d;
    float acc0 = 0, acc1 = 0, acc2 = 0, acc3 = 0;
    float ss0 = 0, ss1 = 0, ss2 = 0, ss3 = 0;
    for (int ml = 0; ml < 512; ++ml) {
        const float vv = bfu(vb[(size_t)ml * 64]);
        const uint2 ee = *(const uint2*)&E2[(size_t)ml * 20 + g * 4];
        float e0, e1, e2, e3;
        bf2(ee.x, e0, e1);
        bf2(ee.y, e2, e3);
        acc0 += e0 * vv; ss0 += e0;
        acc1 += e1 * vv; ss1 += e1;
        acc2 += e2 * vv; ss2 += e2;
        acc3 += e3 * vv; ss3 += e3;
    }
    float* avz = avp + (size_t)(z * 96 + bh) * 1024;
    avz[(g * 4 + 0) * 64 + d] = acc0;
    avz[(g * 4 + 1) * 64 + d] = acc1;
    avz[(g * 4 + 2) * 64 + d] = acc2;
    avz[(g * 4 + 3) * 64 + d] = acc3;
    if (d == 0) {
        float* Sz = Sp + (z * 96 + bh) * 16;
        Sz[g * 4 + 0] = ss0;
        Sz[g * 4 + 1] = ss1;
        Sz[g * 4 + 2] = ss2;
        Sz[g * 4 + 3] = ss3;
    }
}

// ---------- Kernel 5: stage 2 (queries -> agents) + fp32 output ----------
__global__ __launch_bounds__(256) void stage2(
    const ushort_t* __restrict__ q_hm, const float* __restrict__ avp,
    const float* __restrict__ Sp, const float* __restrict__ agent,
    const float* __restrict__ ab, float* __restrict__ out)
{
    const int nb = blockIdx.x, bh = blockIdx.y;
    const int b = bh / 12, h = bh % 12;
    const int tid = threadIdx.x;
    __shared__ float ahs[1024];
    __shared__ float avn[1024];
    __shared__ float abl[16];

    for (int i = tid; i < 1024; i += 256) {
        const int a = i >> 6;
        ahs[i] = agent[(size_t)bh * 1024 + i] * 0.125f;
        float num = 0.f, den = 0.f;
        #pragma unroll
        for (int zz = 0; zz < 8; ++zz) {
            num += avp[(size_t)(zz * 96 + bh) * 1024 + i];
            den += Sp[(zz * 96 + bh) * 16 + a];
        }
        avn[i] = num / den;
    }
    if (tid < 16) abl[tid] = ab[h * 16 + tid];
    __syncthreads();

    const int n0 = nb * 512;
    const uint4* qrA = (const uint4*)(q_hm + ((size_t)bh * 4096 + n0 + tid) * 64);
    const uint4* qrB = (const uint4*)(q_hm + ((size_t)bh * 4096 + n0 + tid + 256) * 64);
    uint quA[16], quB[16];
    #pragma unroll
    for (int i = 0; i < 4; ++i) {
        uint4 ua = qrA[i], ub = qrB[i];
        quA[i*4+0] = ua.x; quA[i*4+1] = ua.y; quA[i*4+2] = ua.z; quA[i*4+3] = ua.w;
        quB[i*4+0] = ub.x; quB[i*4+1] = ub.y; quB[i*4+2] = ub.z; quB[i*4+3] = ub.w;
    }
    float dsA[16], dsB[16];
    #pragma unroll
    for (int a = 0; a < 16; ++a) { float t = abl[a]; dsA[a] = t; dsB[a] = t; }
    #pragma unroll
    for (int c = 0; c < 16; ++c) {
        float a0, a1, a2, a3, b0, b1, b2, b3;
        bf2(quA[2*c],   a0, a1); bf2(quA[2*c+1], a2, a3);
        bf2(quB[2*c],   b0, b1); bf2(quB[2*c+1], b2, b3);
        #pragma unroll
        for (int a = 0; a < 16; ++a) {
            const floatx4 av = *(const floatx4*)&ahs[a * 64 + c * 4];
            dsA[a] += a0 * av[0] + a1 * av[1] + a2 * av[2] + a3 * av[3];
            dsB[a] += b0 * av[0] + b1 * av[1] + b2 * av[2] + b3 * av[3];
        }
    }
    float psA = 0.f, psB = 0.f;
    #pragma unroll
    for (int a = 0; a < 16; ++a) {
        dsA[a] = __expf(dsA[a]); psA += dsA[a];
        dsB[a] = __expf(dsB[a]); psB += dsB[a];
    }
    const float rA = 1.0f / psA, rB = 1.0f / psB;
    #pragma unroll
    for (int a = 0; a < 16; ++a) { dsA[a] *= rA; dsB[a] *= rB; }

    float* oA = out + ((size_t)b * 4096 + n0 + tid) * CDIM + h * 64;
    float* oB = oA + (size_t)256 * CDIM;
    #pragma unroll
    for (int dc = 0; dc < 16; ++dc) {
        floatx4 sA = {0.f, 0.f, 0.f, 0.f}, sB = {0.f, 0.f, 0.f, 0.f};
        #pragma unroll
        for (int a = 0; a < 16; ++a) {
            const floatx4 av = *(const floatx4*)&avn[a * 64 + dc * 4];
            sA += dsA[a] * av;
            sB += dsB[a] * av;
        }
        *(floatx4*)(oA + dc * 4) = sA;
        *(floatx4*)(oB + dc * 4) = sB;
    }
}

// ---------- launcher ----------
extern "C" void kernel_launch(void* const* d_in, const int* in_sizes, int n_in,
                              void* d_out, int out_size, void* d_ws, size_t ws_size,
                              hipStream_t stream) {
    (void)in_sizes; (void)n_in; (void)out_size; (void)ws_size;
    const float* s1 = (const float*)d_in[0];
    const float* s2 = (const float*)d_in[1];
    const float* Wq = (const float*)d_in[2];
    const float* bq = (const float*)d_in[3];
    const float* Wk = (const float*)d_in[4];
    const float* bk = (const float*)d_in[5];
    const float* Wv = (const float*)d_in[6];
    const float* bv = (const float*)d_in[7];
    const float* na = (const float*)d_in[9];
    const float* ha = (const float*)d_in[12];
    const float* wa = (const float*)d_in[13];
    float* out = (float*)d_out;

    char* ws = (char*)d_ws;
    ushort_t* q_hm = (ushort_t*)(ws);                 // 50,331,648 B  [96][4096][64]
    ushort_t* k_hm = (ushort_t*)(ws + 50331648);      // 50,331,648 B
    ushort_t* v_hm = (ushort_t*)(ws + 100663296);     // 50,331,648 B
    float* agent   = (float*)(ws + 150994944);        //    393,216 B  [96][16][64]
    float* Sp      = (float*)(ws + 151388160);        //     49,152 B  [8][96][16]
    float* avp     = (float*)(ws + 151437312);        //  3,145,728 B  [8][96][16][64]
    float* ab      = (float*)(ws + 154583040);        //        768 B
    ushort_t* wb   = (ushort_t*)(ws + 154583808);     //  3,538,944 B  [3][768][768]
    ushort_t* abuf = (ushort_t*)(ws + 158122752);     // 100,663,296 B [2][32768][768]

    cvt_w     <<<dim3(288, 3),    256, 0, stream>>>(Wq, Wk, Wv, wb);
    cvt_a     <<<dim3(12288, 2),  256, 0, stream>>>(s1, s2, abuf);
    gemm_qkv  <<<dim3(256, 6, 3), 256, 0, stream>>>(abuf, wb, bq, bk, bv, q_hm, k_hm, v_hm);
    pool_agent<<<dim3(16, 96),    256, 0, stream>>>(q_hm, agent);
    bias_ab_k <<<1, 256, 0, stream>>>(na, ha, wa, ab);
    stage1    <<<dim3(96, 8),     256, 0, stream>>>(k_hm, v_hm, agent, Sp, avp);
    stage2    <<<dim3(8, 96),     256, 0, stream>>>(q_hm, avp, Sp, agent, ab, out);
}